// Round 8
// baseline (71.200 us; speedup 1.0000x reference)
//
#include <hip/hip_runtime.h>

#define BN_EPS 1e-5f

typedef short short8 __attribute__((ext_vector_type(8)));
typedef float f32x4 __attribute__((ext_vector_type(4)));
typedef unsigned short ushort;

__device__ inline ushort f2bf(float f) {
  unsigned int u = __float_as_uint(f);
  u += 0x7FFFu + ((u >> 16) & 1u);
  return (ushort)(u >> 16);
}

// ws float-word layout:
//   [0..5]           stats (3 sums, 3 sumsqs)
//   [64..119871]     psumS [6][19968]
//   [131072..262143] WgtB  bf16 [8][64][64][8]  (512 KB = 131072 words)
//   [262144..524287] featB bf16 [512][2048]     (2 MB  = 262144 words)
//   [786432..]       S     [9][346112] fp32     (12.5 MB)

#define NPOS 346112  // 512*676
#define LROW 144     // padded LDS row stride
#define NBLK 19968   // 512*3*13

// ---------------- K1: max-occupancy conv partials + fused stats ----------------
// Block = (b, c, band k of 2 output rows): stages input rows 10k-1..10k+8
// (disjoint partition of [-1,128] across k=0..12; pads are zero rows).
__global__ __launch_bounds__(256, 8) void k_convraw(
    const float* __restrict__ x,       // [512,3,128,128]
    const float* __restrict__ w1g,     // [3,3,5,5] wave-uniform (SGPR) loads
    float* __restrict__ S,             // [9][NPOS]
    float* __restrict__ psumS)         // [6][NBLK]
{
  __shared__ float s_xp[10 * LROW];
  __shared__ float red[4][2];
  const int tid = threadIdx.x;
  const int bid = blockIdx.x;          // b*39 + c*13 + k
  const int k = bid % 13;
  const int c = (bid / 13) % 3;
  const int b = bid / 39;

  // zero the column pads (LDS cols 3 and 132) for all 10 rows
  if (tid < 10) {
    s_xp[tid * LROW + 3] = 0.f;
    s_xp[tid * LROW + 132] = 0.f;
  }

  // stage 10 rows x 128 cols (320 float4), zero rows outside [0,128)
  const float* xc = x + ((size_t)b * 3 + c) * 16384;
  float s = 0.f, q = 0.f;
  #pragma unroll
  for (int u = 0; u < 2; u++) {
    int v = tid + u * 256;
    if (v < 320) {
      int j = v >> 5, col4 = (v & 31) << 2;
      int r = 10 * k - 1 + j;
      float4 a4 = {0.f, 0.f, 0.f, 0.f};
      if (r >= 0 && r < 128) a4 = *(const float4*)(xc + r * 128 + col4);
      float* d = &s_xp[j * LROW + col4 + 4];
      d[0] = a4.x; d[1] = a4.y; d[2] = a4.z; d[3] = a4.w;
      s += (a4.x + a4.y) + (a4.z + a4.w);
      q += (a4.x * a4.x + a4.y * a4.y) + (a4.z * a4.z + a4.w * a4.w);
    }
  }
  __syncthreads();

  // compute: wave w in 0..2 = out channel, lanes 0..51 = (2 rows x 26 cols)
  const int w = tid >> 6, lane = tid & 63;
  if (w < 3 && lane < 52) {
    int ol = lane >= 26 ? 1 : 0;
    int ox = lane - ol * 26;
    const float* wk = w1g + w * 75 + c * 25;    // wave-uniform -> s_load
    const float* base = &s_xp[(5 * ol) * LROW + 5 * ox + 3];
    float a = 0.f;
    #pragma unroll
    for (int ky = 0; ky < 5; ky++) {
      #pragma unroll
      for (int kx = 0; kx < 5; kx++)
        a += wk[ky * 5 + kx] * base[ky * LROW + kx];
    }
    int oy = 2 * k + ol;
    S[(size_t)(c * 3 + w) * NPOS + (size_t)b * 676 + oy * 26 + ox] = a;
  }

  // fused stats reduce -> psumS[c][bid], psumS[3+c][bid]
  #pragma unroll
  for (int off = 32; off; off >>= 1) {
    s += __shfl_down(s, off);
    q += __shfl_down(q, off);
  }
  if (lane == 0) { red[w][0] = s; red[w][1] = q; }
  __syncthreads();
  if (tid == 0)
    psumS[(size_t)c * NBLK + bid] = (red[0][0] + red[1][0]) + (red[2][0] + red[3][0]);
  if (tid == 1)
    psumS[(size_t)(3 + c) * NBLK + bid] = (red[0][1] + red[1][1]) + (red[2][1] + red[3][1]);
}

// ---------------- K1b: fold NBLK partials -> 6 stats (one block per stat) ----------------
__global__ __launch_bounds__(1024) void k_reduce(const float* __restrict__ psumS,
                                                 float* __restrict__ stats) {
  const int sidx = blockIdx.x;
  const float* src = psumS + (size_t)sidx * NBLK;
  float acc = 0.f;
  for (int i = threadIdx.x; i < NBLK; i += 1024) acc += src[i];
  #pragma unroll
  for (int off = 32; off; off >>= 1) acc += __shfl_down(acc, off);
  __shared__ float r[16];
  if ((threadIdx.x & 63) == 0) r[threadIdx.x >> 6] = acc;
  __syncthreads();
  if (threadIdx.x == 0) {
    float t = 0.f;
    #pragma unroll
    for (int i = 0; i < 16; i++) t += r[i];
    stats[sidx] = t;
  }
}

// ---------------- Kg: gather live fc1 columns -> bf16 B-fragment layout ----------------
__device__ inline float gval(const float* __restrict__ row, int k) {
  if (k >= 2028) return 0.f;
  int c = k / 676;
  int rem = k - c * 676;
  int oy = rem / 26, ox = rem - oy * 26;
  int col = c * 4225 + ((5 * oy) >> 1) * 65 + ((5 * ox) >> 1);
  return row[col];
}

__global__ __launch_bounds__(256) void k_gather(const float* __restrict__ fc1_w,
                                                ushort* __restrict__ WgtB) {
  int gid = blockIdx.x * 256 + threadIdx.x;  // 32768 total
  int l = gid & 63;
  int n = ((gid >> 12) << 4) + (l & 15);
  int kbase = (((gid >> 6) & 63) << 5) + ((l >> 4) << 3);
  const float* row = fc1_w + n * 12675;
  uint4 o;
  unsigned int w[4];
  #pragma unroll
  for (int i = 0; i < 4; i++) {
    ushort lo = f2bf(gval(row, kbase + 2 * i));
    ushort hi = f2bf(gval(row, kbase + 2 * i + 1));
    w[i] = (unsigned int)lo | ((unsigned int)hi << 16);
  }
  o.x = w[0]; o.y = w[1]; o.z = w[2]; o.w = w[3];
  ((uint4*)WgtB)[gid] = o;
}

// ---------------- K2: combine S + stats -> BN'd conv1 + relu + 1x1 conv2 + relu -> bf16 feat ----
__global__ __launch_bounds__(256) void k_combine(
    const float* __restrict__ S,       // [9][NPOS]
    const float* __restrict__ stats,
    const float* __restrict__ gamma, const float* __restrict__ beta,
    const float* __restrict__ w1, const float* __restrict__ b1,
    const float* __restrict__ w2, const float* __restrict__ b2,
    ushort* __restrict__ featB)        // [512][2048] bf16
{
  __shared__ float s_w1[225];
  __shared__ float s_w2[9];
  __shared__ float s_scale[3], s_shift[3], s_b1[3], s_b2[3];
  __shared__ float s_T[9][9];          // [rcl*3+ccl][o*3+c]
  const int tid = threadIdx.x;
  if (tid < 225) s_w1[tid] = w1[tid];
  if (tid < 9) s_w2[tid] = w2[tid * 25];
  if (tid < 3) {
    const float N = 512.f * 128.f * 128.f;
    float mean = stats[tid] / N;
    float var = stats[3 + tid] / N - mean * mean;
    float sc = gamma[tid] * rsqrtf(var + BN_EPS);
    s_scale[tid] = sc;
    s_shift[tid] = beta[tid] - mean * sc;
    s_b1[tid] = b1[tid];
    s_b2[tid] = b2[tid];
  }
  __syncthreads();
  if (tid < 81) {
    int cls = tid / 9, oc = tid - (tid / 9) * 9;
    int rcl = cls / 3, ccl = cls - rcl * 3;
    int o = oc / 3, c = oc - o * 3;
    int ky0 = (rcl == 0) ? 1 : 0, ky1 = (rcl == 2) ? 3 : 4;
    int kx0 = (ccl == 0) ? 1 : 0, kx1 = (ccl == 2) ? 3 : 4;
    float t = 0.f;
    for (int ky = ky0; ky <= ky1; ky++)
      for (int kx = kx0; kx <= kx1; kx++)
        t += s_w1[o * 75 + c * 25 + ky * 5 + kx];
    s_T[cls][oc] = t;
  }
  __syncthreads();

  int gpos = blockIdx.x * 256 + tid;
  int b = gpos / 676;
  int pos = gpos - b * 676;
  int oy = pos / 26, ox = pos - oy * 26;
  int rcl = (oy == 0) ? 0 : ((oy == 25) ? 2 : 1);
  int ccl = (ox == 0) ? 0 : ((ox == 25) ? 2 : 1);
  int cls = rcl * 3 + ccl;

  float h[3];
  #pragma unroll
  for (int o = 0; o < 3; o++) {
    float a = s_b1[o];
    #pragma unroll
    for (int c = 0; c < 3; c++) {
      a += s_scale[c] * S[(size_t)(c * 3 + o) * NPOS + gpos];
      a += s_shift[c] * s_T[cls][o * 3 + c];
    }
    h[o] = fmaxf(a, 0.f);
  }
  ushort* fb = featB + (size_t)b * 2048;
  #pragma unroll
  for (int o = 0; o < 3; o++) {
    float v = s_b2[o] + s_w2[3 * o] * h[0] + s_w2[3 * o + 1] * h[1] + s_w2[3 * o + 2] * h[2];
    fb[o * 676 + pos] = f2bf(fmaxf(v, 0.f));
  }
  if (pos < 20) fb[2028 + pos] = 0;  // zero K-pad
}

// ---------------- K3: fc1 via MFMA + relu + fc2 + log_softmax ----------------
__global__ __launch_bounds__(512) void k_fc(
    const ushort* __restrict__ featB,  // [512][2048] bf16
    const ushort* __restrict__ WgtB,   // B-fragment layout
    const float* __restrict__ fc1_b,
    const float* __restrict__ fc2_w, const float* __restrict__ fc2_b,
    float* __restrict__ out)           // [512,10]
{
  __shared__ float s_f[16][132];
  __shared__ float s_lg[16][10];
  const int tid = threadIdx.x;
  const int lane = tid & 63;
  const int t = tid >> 6;           // N-tile 0..7
  const int m0 = blockIdx.x * 16;

  const ushort* aptr = featB + (size_t)(m0 + (lane & 15)) * 2048 + ((lane >> 4) << 3);
  const ushort* bptr = WgtB + ((size_t)t * 4096 + lane) * 8;

  f32x4 acc = {0.f, 0.f, 0.f, 0.f};
  #pragma unroll 4
  for (int kk = 0; kk < 64; kk++) {
    short8 a = *(const short8*)(aptr + kk * 32);
    short8 bfr = *(const short8*)(bptr + kk * 512);
    acc = __builtin_amdgcn_mfma_f32_16x16x32_bf16(a, bfr, acc, 0, 0, 0);
  }
  {
    int n = t * 16 + (lane & 15);
    float bias = fc1_b[n];
    int mb = (lane >> 4) << 2;
    #pragma unroll
    for (int r = 0; r < 4; r++)
      s_f[mb + r][n] = fmaxf(acc[r] + bias, 0.f);
  }
  __syncthreads();

  if (tid < 160) {
    int m = tid & 15, q = tid >> 4;
    const float* wr = fc2_w + q * 128;
    float a2 = fc2_b[q];
    #pragma unroll 8
    for (int n = 0; n < 128; n++) a2 += wr[n] * s_f[m][n];
    s_lg[m][q] = a2;
  }
  __syncthreads();

  if (tid < 16) {
    float mx = s_lg[tid][0];
    #pragma unroll
    for (int q = 1; q < 10; q++) mx = fmaxf(mx, s_lg[tid][q]);
    float se = 0.f;
    #pragma unroll
    for (int q = 0; q < 10; q++) se += expf(s_lg[tid][q] - mx);
    float lse = mx + logf(se);
    float* op = out + (size_t)(m0 + tid) * 10;
    #pragma unroll
    for (int q = 0; q < 10; q++) op[q] = s_lg[tid][q] - lse;
  }
}

extern "C" void kernel_launch(void* const* d_in, const int* in_sizes, int n_in,
                              void* d_out, int out_size, void* d_ws, size_t ws_size,
                              hipStream_t stream) {
  const float* x      = (const float*)d_in[0];
  const float* gamma  = (const float*)d_in[1];
  const float* beta   = (const float*)d_in[2];
  const float* w1     = (const float*)d_in[3];
  const float* b1     = (const float*)d_in[4];
  const float* w2     = (const float*)d_in[5];
  const float* b2     = (const float*)d_in[6];
  const float* fc1_w  = (const float*)d_in[7];
  const float* fc1_b  = (const float*)d_in[8];
  const float* fc2_w  = (const float*)d_in[9];
  const float* fc2_b  = (const float*)d_in[10];
  float* out = (float*)d_out;
  float* wsf = (float*)d_ws;

  float* stats  = wsf;                      // [0..5]
  float* psumS  = wsf + 64;                 // [6][19968]
  ushort* WgtB  = (ushort*)(wsf + 131072);  // 512 KB bf16
  ushort* featB = (ushort*)(wsf + 262144);  // 1 MB bf16 elems (2 MB bytes? 512*2048*2B)
  float* S      = wsf + 786432;             // [9][NPOS] = 12.5 MB

  k_convraw<<<NBLK, 256, 0, stream>>>(x, w1, S, psumS);
  k_gather<<<128, 256, 0, stream>>>(fc1_w, WgtB);
  k_reduce<<<6, 1024, 0, stream>>>(psumS, stats);
  k_combine<<<1352, 256, 0, stream>>>(S, stats, gamma, beta, w1, b1, w2, b2, featB);
  k_fc<<<32, 512, 0, stream>>>(featB, WgtB, fc1_b, fc2_w, fc2_b, out);
}

// Round 9
// 70.449 us; speedup vs baseline: 1.0107x; 1.0107x over previous
//
#include <hip/hip_runtime.h>

#define BN_EPS 1e-5f

typedef short short8 __attribute__((ext_vector_type(8)));
typedef float f32x4 __attribute__((ext_vector_type(4)));
typedef unsigned short ushort;

__device__ inline ushort f2bf(float f) {
  unsigned int u = __float_as_uint(f);
  u += 0x7FFFu + ((u >> 16) & 1u);
  return (ushort)(u >> 16);
}

// ws float-word layout:
//   [0..5]           stats (3 sums, 3 sumsqs)
//   [64..1599]       psum[1536]
//   [1664..3199]     psq[1536]
//   [16384..147455]  WgtB  bf16 [8][64][64][8]  (512 KB)
//   [262144..524287] featB bf16 [512][2048]     (2 MB)

#define LROW 144     // padded LDS row stride

// ---------------- K1: per-plane sum / sumsq over x (pure stream, no atomics) ----------------
__global__ __launch_bounds__(256) void k_stats(const float4* __restrict__ x4,
                                               float* __restrict__ psum,
                                               float* __restrict__ psq) {
  const int p = blockIdx.x;  // plane id: b*3 + c
  const float4* base = x4 + (size_t)p * 4096;
  float s = 0.f, q = 0.f;
  #pragma unroll
  for (int i = 0; i < 16; i++) {
    float4 a = base[i * 256 + threadIdx.x];
    s += (a.x + a.y) + (a.z + a.w);
    q += (a.x * a.x + a.y * a.y) + (a.z * a.z + a.w * a.w);
  }
  #pragma unroll
  for (int off = 32; off; off >>= 1) {
    s += __shfl_down(s, off);
    q += __shfl_down(q, off);
  }
  __shared__ float rs[4], rq[4];
  int lane = threadIdx.x & 63, w = threadIdx.x >> 6;
  if (lane == 0) { rs[w] = s; rq[w] = q; }
  __syncthreads();
  if (threadIdx.x == 0) {
    psum[p] = (rs[0] + rs[1]) + (rs[2] + rs[3]);
    psq[p]  = (rq[0] + rq[1]) + (rq[2] + rq[3]);
  }
}

// ---------------- K1b: fold 1536 partials -> 6 stats ----------------
__global__ __launch_bounds__(384) void k_reduce(const float* __restrict__ psum,
                                                const float* __restrict__ psq,
                                                float* __restrict__ stats) {
  int w = threadIdx.x >> 6, lane = threadIdx.x & 63;
  const float* src = (w < 3) ? psum : psq;
  int c = (w < 3) ? w : (w - 3);
  float acc = 0.f;
  #pragma unroll
  for (int k = 0; k < 8; k++) acc += src[3 * (lane + 64 * k) + c];
  #pragma unroll
  for (int off = 32; off; off >>= 1) acc += __shfl_down(acc, off);
  if (lane == 0) stats[w] = acc;
}

// ---------------- Kg: gather live fc1 columns -> bf16 B-fragment layout; zero feat K-pad ----
__device__ inline float gval(const float* __restrict__ row, int k) {
  if (k >= 2028) return 0.f;
  int c = k / 676;
  int rem = k - c * 676;
  int oy = rem / 26, ox = rem - oy * 26;
  int col = c * 4225 + ((5 * oy) >> 1) * 65 + ((5 * ox) >> 1);
  return row[col];
}

__global__ __launch_bounds__(256) void k_gather(const float* __restrict__ fc1_w,
                                                ushort* __restrict__ WgtB,
                                                ushort* __restrict__ featB) {
  int gid = blockIdx.x * 256 + threadIdx.x;  // 32768 total
  if (gid < 10240)  // zero featB[:, 2028:2048]
    featB[(size_t)(gid / 20) * 2048 + 2028 + (gid % 20)] = 0;
  int l = gid & 63;
  int n = ((gid >> 12) << 4) + (l & 15);
  int kbase = (((gid >> 6) & 63) << 5) + ((l >> 4) << 3);
  const float* row = fc1_w + n * 12675;
  uint4 o;
  unsigned int w[4];
  #pragma unroll
  for (int i = 0; i < 4; i++) {
    ushort lo = f2bf(gval(row, kbase + 2 * i));
    ushort hi = f2bf(gval(row, kbase + 2 * i + 1));
    w[i] = (unsigned int)lo | ((unsigned int)hi << 16);
  }
  o.x = w[0]; o.y = w[1]; o.z = w[2]; o.w = w[3];
  ((uint4*)WgtB)[gid] = o;
}

// ---------------- K2: BN@stage + conv1 + relu + 1x1 conv2 + relu -> bf16 feat ----------------
// Block = (b, band k): stages rows 10k-1..10k+8 of ALL 3 channels, BN-transformed
// (pads = 0, matching pad-after-BN). 6656 blocks, 17.9 KB LDS -> 8 blocks/CU.
__global__ __launch_bounds__(256) void k_convfeat(
    const float* __restrict__ x,       // [512,3,128,128]
    const float* __restrict__ stats,
    const float* __restrict__ gamma, const float* __restrict__ beta,
    const float* __restrict__ w1g,     // [3,3,5,5] wave-uniform loads
    const float* __restrict__ b1,
    const float* __restrict__ w2g, const float* __restrict__ b2,
    ushort* __restrict__ featB)        // [512][2048] bf16
{
  __shared__ float s_xp[3][10 * LROW];
  __shared__ float s_h[3][52];
  const int tid = threadIdx.x;
  const int bid = blockIdx.x;          // b*13 + k
  const int k = bid % 13;
  const int b = bid / 13;

  // per-channel BN affine (uniform scalar math)
  float sc[3], sh[3];
  const float N = 512.f * 128.f * 128.f;
  #pragma unroll
  for (int c = 0; c < 3; c++) {
    float mean = stats[c] / N;
    float var = stats[3 + c] / N - mean * mean;
    float s = gamma[c] * rsqrtf(var + BN_EPS);
    sc[c] = s;
    sh[c] = beta[c] - mean * s;
  }

  // column pads (LDS cols 3 and 132), all 3 channels x 10 rows
  if (tid < 60) {
    int c = tid / 20, rr = (tid % 20) >> 1, side = tid & 1;
    s_xp[c][rr * LROW + (side ? 132 : 3)] = 0.f;
  }

  // stage: 3 planes x 10 rows x 128 cols = 960 float4, BN applied, OOB rows = 0
  const float* xb = x + (size_t)b * 49152;
  #pragma unroll
  for (int u = 0; u < 4; u++) {
    int v = tid + u * 256;
    if (v < 960) {
      int c = v / 320, vv = v - c * 320;
      int j = vv >> 5, col4 = (vv & 31) << 2;
      int r = 10 * k - 1 + j;
      float4 a4 = {0.f, 0.f, 0.f, 0.f};
      if (r >= 0 && r < 128) {
        a4 = *(const float4*)(xb + c * 16384 + r * 128 + col4);
        a4.x = a4.x * sc[c] + sh[c];
        a4.y = a4.y * sc[c] + sh[c];
        a4.z = a4.z * sc[c] + sh[c];
        a4.w = a4.w * sc[c] + sh[c];
      }
      float* d = &s_xp[c][j * LROW + col4 + 4];
      d[0] = a4.x; d[1] = a4.y; d[2] = a4.z; d[3] = a4.w;
    }
  }
  __syncthreads();

  // conv1: wave w = out channel, lanes 0..51 = (2 out rows x 26 cols)
  const int w = tid >> 6, lane = tid & 63;
  if (w < 3 && lane < 52) {
    int ol = lane >= 26 ? 1 : 0;
    int ox = lane - ol * 26;
    float a = b1[w];
    #pragma unroll
    for (int c = 0; c < 3; c++) {
      const float* wk = w1g + w * 75 + c * 25;        // wave-uniform -> s_load
      const float* base = &s_xp[c][(5 * ol) * LROW + 5 * ox + 3];
      #pragma unroll
      for (int ky = 0; ky < 5; ky++) {
        #pragma unroll
        for (int kx = 0; kx < 5; kx++)
          a += wk[ky * 5 + kx] * base[ky * LROW + kx];
      }
    }
    s_h[w][lane] = fmaxf(a, 0.f);
  }
  __syncthreads();

  // 1x1 conv2 + relu -> featB
  if (tid < 52) {
    int ol = tid >= 26 ? 1 : 0;
    int ox = tid - ol * 26;
    float h0 = s_h[0][tid], h1 = s_h[1][tid], h2 = s_h[2][tid];
    int oy = 2 * k + ol;
    ushort* fb = featB + (size_t)b * 2048 + oy * 26 + ox;
    #pragma unroll
    for (int o = 0; o < 3; o++) {
      float v = b2[o] + w2g[o * 75] * h0 + w2g[o * 75 + 25] * h1 + w2g[o * 75 + 50] * h2;
      fb[o * 676] = f2bf(fmaxf(v, 0.f));
    }
  }
}

// ---------------- K3: fc1 via MFMA + relu + fc2 + log_softmax ----------------
__global__ __launch_bounds__(512) void k_fc(
    const ushort* __restrict__ featB,  // [512][2048] bf16
    const ushort* __restrict__ WgtB,   // B-fragment layout
    const float* __restrict__ fc1_b,
    const float* __restrict__ fc2_w, const float* __restrict__ fc2_b,
    float* __restrict__ out)           // [512,10]
{
  __shared__ float s_f[16][132];
  __shared__ float s_lg[16][10];
  const int tid = threadIdx.x;
  const int lane = tid & 63;
  const int t = tid >> 6;           // N-tile 0..7
  const int m0 = blockIdx.x * 16;

  const ushort* aptr = featB + (size_t)(m0 + (lane & 15)) * 2048 + ((lane >> 4) << 3);
  const ushort* bptr = WgtB + ((size_t)t * 4096 + lane) * 8;

  f32x4 acc = {0.f, 0.f, 0.f, 0.f};
  #pragma unroll 4
  for (int kk = 0; kk < 64; kk++) {
    short8 a = *(const short8*)(aptr + kk * 32);
    short8 bfr = *(const short8*)(bptr + kk * 512);
    acc = __builtin_amdgcn_mfma_f32_16x16x32_bf16(a, bfr, acc, 0, 0, 0);
  }
  {
    int n = t * 16 + (lane & 15);
    float bias = fc1_b[n];
    int mb = (lane >> 4) << 2;
    #pragma unroll
    for (int r = 0; r < 4; r++)
      s_f[mb + r][n] = fmaxf(acc[r] + bias, 0.f);
  }
  __syncthreads();

  if (tid < 160) {
    int m = tid & 15, q = tid >> 4;
    const float* wr = fc2_w + q * 128;
    float a2 = fc2_b[q];
    #pragma unroll 8
    for (int n = 0; n < 128; n++) a2 += wr[n] * s_f[m][n];
    s_lg[m][q] = a2;
  }
  __syncthreads();

  if (tid < 16) {
    float mx = s_lg[tid][0];
    #pragma unroll
    for (int q = 1; q < 10; q++) mx = fmaxf(mx, s_lg[tid][q]);
    float se = 0.f;
    #pragma unroll
    for (int q = 0; q < 10; q++) se += expf(s_lg[tid][q] - mx);
    float lse = mx + logf(se);
    float* op = out + (size_t)(m0 + tid) * 10;
    #pragma unroll
    for (int q = 0; q < 10; q++) op[q] = s_lg[tid][q] - lse;
  }
}

extern "C" void kernel_launch(void* const* d_in, const int* in_sizes, int n_in,
                              void* d_out, int out_size, void* d_ws, size_t ws_size,
                              hipStream_t stream) {
  const float* x      = (const float*)d_in[0];
  const float* gamma  = (const float*)d_in[1];
  const float* beta   = (const float*)d_in[2];
  const float* w1     = (const float*)d_in[3];
  const float* b1     = (const float*)d_in[4];
  const float* w2     = (const float*)d_in[5];
  const float* b2     = (const float*)d_in[6];
  const float* fc1_w  = (const float*)d_in[7];
  const float* fc1_b  = (const float*)d_in[8];
  const float* fc2_w  = (const float*)d_in[9];
  const float* fc2_b  = (const float*)d_in[10];
  float* out = (float*)d_out;
  float* wsf = (float*)d_ws;

  float* stats  = wsf;                      // [0..5]
  float* psum   = wsf + 64;                 // 1536
  float* psq    = wsf + 1664;               // 1536
  ushort* WgtB  = (ushort*)(wsf + 16384);   // 512 KB bf16
  ushort* featB = (ushort*)(wsf + 262144);  // 2 MB bf16

  k_stats<<<1536, 256, 0, stream>>>((const float4*)x, psum, psq);
  k_reduce<<<1, 384, 0, stream>>>(psum, psq, stats);
  k_gather<<<128, 256, 0, stream>>>(fc1_w, WgtB, featB);
  k_convfeat<<<6656, 256, 0, stream>>>(x, stats, gamma, beta, w1, b1, w2, b2, featB);
  k_fc<<<32, 512, 0, stream>>>(featB, WgtB, fc1_b, fc2_w, fc2_b, out);
}

// Round 10
// 69.359 us; speedup vs baseline: 1.0265x; 1.0157x over previous
//
#include <hip/hip_runtime.h>

#define BN_EPS 1e-5f

typedef short short8 __attribute__((ext_vector_type(8)));
typedef float f32x4 __attribute__((ext_vector_type(4)));
typedef unsigned short ushort;

__device__ inline ushort f2bf(float f) {
  unsigned int u = __float_as_uint(f);
  u += 0x7FFFu + ((u >> 16) & 1u);
  return (ushort)(u >> 16);
}

// ws float-word layout:
//   [0..5]           stats (3 sums, 3 sumsqs)
//   [64..1599]       psum[1536]
//   [1664..3199]     psq[1536]
//   [16384..147455]  WgtB  bf16 [8][64][64][8]  (512 KB)
//   [262144..524287] featB bf16 [512][2048]     (2 MB)

#define LROW 144     // padded LDS row stride

// ---------------- K1: per-plane sum / sumsq over x (pure stream, no atomics) ----------------
__global__ __launch_bounds__(256) void k_stats(const float4* __restrict__ x4,
                                               float* __restrict__ psum,
                                               float* __restrict__ psq) {
  const int p = blockIdx.x;  // plane id: b*3 + c
  const float4* base = x4 + (size_t)p * 4096;
  float s = 0.f, q = 0.f;
  #pragma unroll
  for (int i = 0; i < 16; i++) {
    float4 a = base[i * 256 + threadIdx.x];
    s += (a.x + a.y) + (a.z + a.w);
    q += (a.x * a.x + a.y * a.y) + (a.z * a.z + a.w * a.w);
  }
  #pragma unroll
  for (int off = 32; off; off >>= 1) {
    s += __shfl_down(s, off);
    q += __shfl_down(q, off);
  }
  __shared__ float rs[4], rq[4];
  int lane = threadIdx.x & 63, w = threadIdx.x >> 6;
  if (lane == 0) { rs[w] = s; rq[w] = q; }
  __syncthreads();
  if (threadIdx.x == 0) {
    psum[p] = (rs[0] + rs[1]) + (rs[2] + rs[3]);
    psq[p]  = (rq[0] + rq[1]) + (rq[2] + rq[3]);
  }
}

// ---------------- K1b: fold 1536 partials -> 6 stats ----------------
__global__ __launch_bounds__(384) void k_reduce(const float* __restrict__ psum,
                                                const float* __restrict__ psq,
                                                float* __restrict__ stats) {
  int w = threadIdx.x >> 6, lane = threadIdx.x & 63;
  const float* src = (w < 3) ? psum : psq;
  int c = (w < 3) ? w : (w - 3);
  float acc = 0.f;
  #pragma unroll
  for (int k = 0; k < 8; k++) acc += src[3 * (lane + 64 * k) + c];
  #pragma unroll
  for (int off = 32; off; off >>= 1) acc += __shfl_down(acc, off);
  if (lane == 0) stats[w] = acc;
}

// ---------------- Kg: gather live fc1 columns -> bf16 B-fragment layout; zero feat K-pad ----
__device__ inline float gval(const float* __restrict__ row, int k) {
  if (k >= 2028) return 0.f;
  int c = k / 676;
  int rem = k - c * 676;
  int oy = rem / 26, ox = rem - oy * 26;
  int col = c * 4225 + ((5 * oy) >> 1) * 65 + ((5 * ox) >> 1);
  return row[col];
}

__global__ __launch_bounds__(256) void k_gather(const float* __restrict__ fc1_w,
                                                ushort* __restrict__ WgtB,
                                                ushort* __restrict__ featB) {
  int gid = blockIdx.x * 256 + threadIdx.x;  // 32768 total
  if (gid < 10240)  // zero featB[:, 2028:2048]
    featB[(size_t)(gid / 20) * 2048 + 2028 + (gid % 20)] = 0;
  int l = gid & 63;
  int n = ((gid >> 12) << 4) + (l & 15);
  int kbase = (((gid >> 6) & 63) << 5) + ((l >> 4) << 3);
  const float* row = fc1_w + n * 12675;
  uint4 o;
  unsigned int w[4];
  #pragma unroll
  for (int i = 0; i < 4; i++) {
    ushort lo = f2bf(gval(row, kbase + 2 * i));
    ushort hi = f2bf(gval(row, kbase + 2 * i + 1));
    w[i] = (unsigned int)lo | ((unsigned int)hi << 16);
  }
  o.x = w[0]; o.y = w[1]; o.z = w[2]; o.w = w[3];
  ((uint4*)WgtB)[gid] = o;
}

// ---------------- K2: BN@stage + conv1 + relu + 1x1 conv2 + relu -> bf16 feat ----------------
// Block = (b, band k): stages rows 10k-1..10k+8 of ALL 3 channels, BN-transformed
// (pads = 0, matching pad-after-BN). 6656 blocks, 17.9 KB LDS -> 8 blocks/CU.
// Weight addressing forced wave-uniform via readfirstlane -> s_load, not flat VMEM.
__global__ __launch_bounds__(256) void k_convfeat(
    const float* __restrict__ x,       // [512,3,128,128]
    const float* __restrict__ stats,
    const float* __restrict__ gamma, const float* __restrict__ beta,
    const float* __restrict__ w1g,     // [3,3,5,5]
    const float* __restrict__ b1,
    const float* __restrict__ w2g, const float* __restrict__ b2,
    ushort* __restrict__ featB)        // [512][2048] bf16
{
  __shared__ float s_xp[3][10 * LROW];
  __shared__ float s_h[3][52];
  const int tid = threadIdx.x;
  const int bid = blockIdx.x;          // b*13 + k
  const int k = bid % 13;
  const int b = bid / 13;

  // per-channel BN affine (uniform scalar math)
  float sc[3], sh[3];
  const float N = 512.f * 128.f * 128.f;
  #pragma unroll
  for (int c = 0; c < 3; c++) {
    float mean = stats[c] / N;
    float var = stats[3 + c] / N - mean * mean;
    float s = gamma[c] * rsqrtf(var + BN_EPS);
    sc[c] = s;
    sh[c] = beta[c] - mean * s;
  }

  // column pads (LDS cols 3 and 132), all 3 channels x 10 rows
  if (tid < 60) {
    int c = tid / 20, rr = (tid % 20) >> 1, side = tid & 1;
    s_xp[c][rr * LROW + (side ? 132 : 3)] = 0.f;
  }

  // stage: 3 planes x 10 rows x 128 cols = 960 float4, BN applied, OOB rows = 0
  const float* xb = x + (size_t)b * 49152;
  #pragma unroll
  for (int u = 0; u < 4; u++) {
    int v = tid + u * 256;
    if (v < 960) {
      int c = v / 320, vv = v - c * 320;
      int j = vv >> 5, col4 = (vv & 31) << 2;
      int r = 10 * k - 1 + j;
      float4 a4 = {0.f, 0.f, 0.f, 0.f};
      if (r >= 0 && r < 128) {
        a4 = *(const float4*)(xb + c * 16384 + r * 128 + col4);
        a4.x = a4.x * sc[c] + sh[c];
        a4.y = a4.y * sc[c] + sh[c];
        a4.z = a4.z * sc[c] + sh[c];
        a4.w = a4.w * sc[c] + sh[c];
      }
      float* d = &s_xp[c][j * LROW + col4 + 4];
      d[0] = a4.x; d[1] = a4.y; d[2] = a4.z; d[3] = a4.w;
    }
  }
  __syncthreads();

  // conv1: wave wu = out channel (wave-uniform via readfirstlane -> SGPR weight loads),
  // lanes 0..51 = (2 out rows x 26 cols)
  const int lane = tid & 63;
  const int wu = __builtin_amdgcn_readfirstlane(tid >> 6);
  if (wu < 3 && lane < 52) {
    int ol = lane >= 26 ? 1 : 0;
    int ox = lane - ol * 26;
    float a = b1[wu];                                // SGPR-indexed -> s_load
    #pragma unroll
    for (int c = 0; c < 3; c++) {
      const float* wk = w1g + wu * 75 + c * 25;      // SGPR base -> s_load taps
      const float* base = &s_xp[c][(5 * ol) * LROW + 5 * ox + 3];
      #pragma unroll
      for (int ky = 0; ky < 5; ky++) {
        #pragma unroll
        for (int kx = 0; kx < 5; kx++)
          a += wk[ky * 5 + kx] * base[ky * LROW + kx];
      }
    }
    s_h[wu][lane] = fmaxf(a, 0.f);
  }
  __syncthreads();

  // 1x1 conv2 + relu -> featB
  if (tid < 52) {
    int ol = tid >= 26 ? 1 : 0;
    int ox = tid - ol * 26;
    float h0 = s_h[0][tid], h1 = s_h[1][tid], h2 = s_h[2][tid];
    int oy = 2 * k + ol;
    ushort* fb = featB + (size_t)b * 2048 + oy * 26 + ox;
    #pragma unroll
    for (int o = 0; o < 3; o++) {
      float v = b2[o] + w2g[o * 75] * h0 + w2g[o * 75 + 25] * h1 + w2g[o * 75 + 50] * h2;
      fb[o * 676] = f2bf(fmaxf(v, 0.f));
    }
  }
}

// ---------------- K3: fc1 via MFMA + relu + fc2 + log_softmax ----------------
__global__ __launch_bounds__(512) void k_fc(
    const ushort* __restrict__ featB,  // [512][2048] bf16
    const ushort* __restrict__ WgtB,   // B-fragment layout
    const float* __restrict__ fc1_b,
    const float* __restrict__ fc2_w, const float* __restrict__ fc2_b,
    float* __restrict__ out)           // [512,10]
{
  __shared__ float s_f[16][132];
  __shared__ float s_lg[16][10];
  const int tid = threadIdx.x;
  const int lane = tid & 63;
  const int t = tid >> 6;           // N-tile 0..7
  const int m0 = blockIdx.x * 16;

  const ushort* aptr = featB + (size_t)(m0 + (lane & 15)) * 2048 + ((lane >> 4) << 3);
  const ushort* bptr = WgtB + ((size_t)t * 4096 + lane) * 8;

  f32x4 acc = {0.f, 0.f, 0.f, 0.f};
  #pragma unroll 4
  for (int kk = 0; kk < 64; kk++) {
    short8 a = *(const short8*)(aptr + kk * 32);
    short8 bfr = *(const short8*)(bptr + kk * 512);
    acc = __builtin_amdgcn_mfma_f32_16x16x32_bf16(a, bfr, acc, 0, 0, 0);
  }
  {
    int n = t * 16 + (lane & 15);
    float bias = fc1_b[n];
    int mb = (lane >> 4) << 2;
    #pragma unroll
    for (int r = 0; r < 4; r++)
      s_f[mb + r][n] = fmaxf(acc[r] + bias, 0.f);
  }
  __syncthreads();

  if (tid < 160) {
    int m = tid & 15, q = tid >> 4;
    const float* wr = fc2_w + q * 128;
    float a2 = fc2_b[q];
    #pragma unroll 8
    for (int n = 0; n < 128; n++) a2 += wr[n] * s_f[m][n];
    s_lg[m][q] = a2;
  }
  __syncthreads();

  if (tid < 16) {
    float mx = s_lg[tid][0];
    #pragma unroll
    for (int q = 1; q < 10; q++) mx = fmaxf(mx, s_lg[tid][q]);
    float se = 0.f;
    #pragma unroll
    for (int q = 0; q < 10; q++) se += expf(s_lg[tid][q] - mx);
    float lse = mx + logf(se);
    float* op = out + (size_t)(m0 + tid) * 10;
    #pragma unroll
    for (int q = 0; q < 10; q++) op[q] = s_lg[tid][q] - lse;
  }
}

extern "C" void kernel_launch(void* const* d_in, const int* in_sizes, int n_in,
                              void* d_out, int out_size, void* d_ws, size_t ws_size,
                              hipStream_t stream) {
  const float* x      = (const float*)d_in[0];
  const float* gamma  = (const float*)d_in[1];
  const float* beta   = (const float*)d_in[2];
  const float* w1     = (const float*)d_in[3];
  const float* b1     = (const float*)d_in[4];
  const float* w2     = (const float*)d_in[5];
  const float* b2     = (const float*)d_in[6];
  const float* fc1_w  = (const float*)d_in[7];
  const float* fc1_b  = (const float*)d_in[8];
  const float* fc2_w  = (const float*)d_in[9];
  const float* fc2_b  = (const float*)d_in[10];
  float* out = (float*)d_out;
  float* wsf = (float*)d_ws;

  float* stats  = wsf;                      // [0..5]
  float* psum   = wsf + 64;                 // 1536
  float* psq    = wsf + 1664;               // 1536
  ushort* WgtB  = (ushort*)(wsf + 16384);   // 512 KB bf16
  ushort* featB = (ushort*)(wsf + 262144);  // 2 MB bf16

  k_stats<<<1536, 256, 0, stream>>>((const float4*)x, psum, psq);
  k_reduce<<<1, 384, 0, stream>>>(psum, psq, stats);
  k_gather<<<128, 256, 0, stream>>>(fc1_w, WgtB, featB);
  k_convfeat<<<6656, 256, 0, stream>>>(x, stats, gamma, beta, w1, b1, w2, b2, featB);
  k_fc<<<32, 512, 0, stream>>>(featB, WgtB, fc1_b, fc2_w, fc2_b, out);
}

// Round 11
// 60.802 us; speedup vs baseline: 1.1710x; 1.1407x over previous
//
#include <hip/hip_runtime.h>

#define BN_EPS 1e-5f

typedef short short8 __attribute__((ext_vector_type(8)));
typedef float f32x4 __attribute__((ext_vector_type(4)));
typedef unsigned short ushort;

__device__ inline ushort f2bf(float f) {
  unsigned int u = __float_as_uint(f);
  u += 0x7FFFu + ((u >> 16) & 1u);
  return (ushort)(u >> 16);
}

// ws float-word layout:
//   [0..5]           stats (3 sums, 3 sumsqs)
//   [64..39999]      psumA [6][6656]
//   [131072..262143] WgtB  bf16 [8][64][64][8]  (512 KB)
//   [262144..524287] featB bf16 [512][2048]     (2 MB)
//   [786432..]       S     [9][346112] fp32     (12.5 MB)

#define NPOS 346112  // 512*676
#define LR 136       // per-wave LDS row stride (floats)
#define NW 6656      // 512*13 partial slots per stat

// ---------------- K1: barrier-free wave-private conv + fused stats ----------------
// Wave = (b, c, band of 2 output rows). Each wave stages input rows 10*band-1..10*band+8
// into its OWN LDS slice (no __syncthreads anywhere), computes 3 per-channel conv
// partials for 52 positions, and reduces its own stats via shuffles.
__global__ __launch_bounds__(256) void k_convwave(
    const float* __restrict__ x,       // [512,3,128,128]
    const float* __restrict__ w1g,     // [3,3,5,5]
    float* __restrict__ S,             // [9][NPOS]
    float* __restrict__ psumA)         // [6][NW]
{
  __shared__ float lds[4][10 * LR];    // 21.76 KB, one slice per wave
  const int tid = threadIdx.x;
  const int lane = tid & 63;
  const int w = tid >> 6;
  float* sx = lds[w];

  const int widx = blockIdx.x * 4 + w; // 0..19967
  const int b = widx / 39;
  const int r39 = widx - b * 39;
  const int c = r39 / 13;
  const int band = r39 - c * 13;
  const int cu = __builtin_amdgcn_readfirstlane(c);

  // zero the column pads of this wave's slice (cols 3 and 132, 10 rows)
  if (lane < 10) sx[lane * LR + 3] = 0.f;
  else if (lane < 20) sx[(lane - 10) * LR + 132] = 0.f;

  // stage 10 rows x 128 cols (320 float4, 5 per lane), OOB rows = 0; fused stats
  const float* xc = x + ((size_t)b * 3 + c) * 16384;
  const int rbase = 10 * band - 1;
  float s = 0.f, q = 0.f;
  #pragma unroll
  for (int u = 0; u < 5; u++) {
    int v = lane + 64 * u;             // 0..319
    int j = v >> 5;
    int col4 = (v & 31) << 2;
    int r = rbase + j;
    float4 a4 = {0.f, 0.f, 0.f, 0.f};
    if (r >= 0 && r < 128) a4 = *(const float4*)(xc + r * 128 + col4);
    *(float4*)(&sx[j * LR + col4 + 4]) = a4;
    s += (a4.x + a4.y) + (a4.z + a4.w);
    q += (a4.x * a4.x + a4.y * a4.y) + (a4.z * a4.z + a4.w * a4.w);
  }
  // no barrier: LDS slice is wave-private; compiler orders ds_write->ds_read via lgkmcnt

  // compute: lanes 0..25 -> out row 2*band, lanes 32..57 -> out row 2*band+1
  const int ol = lane >> 5;
  const int ox = lane & 31;
  if (ox < 26) {
    const float* base = &sx[(5 * ol) * LR + 5 * ox + 3];
    const float* wk = w1g + cu * 25;   // SGPR base -> scalar tap loads
    float a0 = 0.f, a1 = 0.f, a2 = 0.f;
    #pragma unroll
    for (int ky = 0; ky < 5; ky++) {
      #pragma unroll
      for (int kx = 0; kx < 5; kx++) {
        float vv = base[ky * LR + kx];
        a0 += wk[ky * 5 + kx] * vv;
        a1 += wk[75 + ky * 5 + kx] * vv;
        a2 += wk[150 + ky * 5 + kx] * vv;
      }
    }
    int oy = 2 * band + ol;
    size_t gp = (size_t)b * 676 + oy * 26 + ox;
    S[(size_t)(c * 3 + 0) * NPOS + gp] = a0;
    S[(size_t)(c * 3 + 1) * NPOS + gp] = a1;
    S[(size_t)(c * 3 + 2) * NPOS + gp] = a2;
  }

  // wave-local stats reduction -> psumA
  #pragma unroll
  for (int off = 32; off; off >>= 1) {
    s += __shfl_down(s, off);
    q += __shfl_down(q, off);
  }
  if (lane == 0) {
    int pos = b * 13 + band;
    psumA[(size_t)c * NW + pos] = s;
    psumA[(size_t)(3 + c) * NW + pos] = q;
  }
}

// ---------------- K1b: fold NW partials -> 6 stats (one block per stat) ----------------
__global__ __launch_bounds__(1024) void k_reduce(const float* __restrict__ psumA,
                                                 float* __restrict__ stats) {
  const int sidx = blockIdx.x;
  const float* src = psumA + (size_t)sidx * NW;
  float acc = 0.f;
  for (int i = threadIdx.x; i < NW; i += 1024) acc += src[i];
  #pragma unroll
  for (int off = 32; off; off >>= 1) acc += __shfl_down(acc, off);
  __shared__ float r[16];
  if ((threadIdx.x & 63) == 0) r[threadIdx.x >> 6] = acc;
  __syncthreads();
  if (threadIdx.x == 0) {
    float t = 0.f;
    #pragma unroll
    for (int i = 0; i < 16; i++) t += r[i];
    stats[sidx] = t;
  }
}

// ---------------- Kg: gather live fc1 columns -> bf16 B-fragment layout; zero feat K-pad ----
__device__ inline float gval(const float* __restrict__ row, int k) {
  if (k >= 2028) return 0.f;
  int c = k / 676;
  int rem = k - c * 676;
  int oy = rem / 26, ox = rem - oy * 26;
  int col = c * 4225 + ((5 * oy) >> 1) * 65 + ((5 * ox) >> 1);
  return row[col];
}

__global__ __launch_bounds__(256) void k_gather(const float* __restrict__ fc1_w,
                                                ushort* __restrict__ WgtB,
                                                ushort* __restrict__ featB) {
  int gid = blockIdx.x * 256 + threadIdx.x;  // 32768 total
  if (gid < 10240)  // zero featB[:, 2028:2048]
    featB[(size_t)(gid / 20) * 2048 + 2028 + (gid % 20)] = 0;
  int l = gid & 63;
  int n = ((gid >> 12) << 4) + (l & 15);
  int kbase = (((gid >> 6) & 63) << 5) + ((l >> 4) << 3);
  const float* row = fc1_w + n * 12675;
  uint4 o;
  unsigned int w[4];
  #pragma unroll
  for (int i = 0; i < 4; i++) {
    ushort lo = f2bf(gval(row, kbase + 2 * i));
    ushort hi = f2bf(gval(row, kbase + 2 * i + 1));
    w[i] = (unsigned int)lo | ((unsigned int)hi << 16);
  }
  o.x = w[0]; o.y = w[1]; o.z = w[2]; o.w = w[3];
  ((uint4*)WgtB)[gid] = o;
}

// ---------------- K2: combine S + stats -> BN'd conv1 + relu + 1x1 conv2 + relu -> bf16 feat ----
__global__ __launch_bounds__(256) void k_combine(
    const float* __restrict__ S,       // [9][NPOS]
    const float* __restrict__ stats,
    const float* __restrict__ gamma, const float* __restrict__ beta,
    const float* __restrict__ w1, const float* __restrict__ b1,
    const float* __restrict__ w2, const float* __restrict__ b2,
    ushort* __restrict__ featB)        // [512][2048] bf16
{
  __shared__ float s_w1[225];
  __shared__ float s_w2[9];
  __shared__ float s_scale[3], s_shift[3], s_b1[3], s_b2[3];
  __shared__ float s_T[9][9];          // [rcl*3+ccl][o*3+c]
  const int tid = threadIdx.x;
  if (tid < 225) s_w1[tid] = w1[tid];
  if (tid < 9) s_w2[tid] = w2[tid * 25];
  if (tid < 3) {
    const float N = 512.f * 128.f * 128.f;
    float mean = stats[tid] / N;
    float var = stats[3 + tid] / N - mean * mean;
    float sc = gamma[tid] * rsqrtf(var + BN_EPS);
    s_scale[tid] = sc;
    s_shift[tid] = beta[tid] - mean * sc;
    s_b1[tid] = b1[tid];
    s_b2[tid] = b2[tid];
  }
  __syncthreads();
  if (tid < 81) {
    int cls = tid / 9, oc = tid - (tid / 9) * 9;
    int rcl = cls / 3, ccl = cls - rcl * 3;
    int o = oc / 3, c = oc - o * 3;
    int ky0 = (rcl == 0) ? 1 : 0, ky1 = (rcl == 2) ? 3 : 4;
    int kx0 = (ccl == 0) ? 1 : 0, kx1 = (ccl == 2) ? 3 : 4;
    float t = 0.f;
    for (int ky = ky0; ky <= ky1; ky++)
      for (int kx = kx0; kx <= kx1; kx++)
        t += s_w1[o * 75 + c * 25 + ky * 5 + kx];
    s_T[cls][oc] = t;
  }
  __syncthreads();

  int gpos = blockIdx.x * 256 + tid;
  int b = gpos / 676;
  int pos = gpos - b * 676;
  int oy = pos / 26, ox = pos - oy * 26;
  int rcl = (oy == 0) ? 0 : ((oy == 25) ? 2 : 1);
  int ccl = (ox == 0) ? 0 : ((ox == 25) ? 2 : 1);
  int cls = rcl * 3 + ccl;

  float h[3];
  #pragma unroll
  for (int o = 0; o < 3; o++) {
    float a = s_b1[o];
    #pragma unroll
    for (int c = 0; c < 3; c++) {
      a += s_scale[c] * S[(size_t)(c * 3 + o) * NPOS + gpos];
      a += s_shift[c] * s_T[cls][o * 3 + c];
    }
    h[o] = fmaxf(a, 0.f);
  }
  ushort* fb = featB + (size_t)b * 2048;
  #pragma unroll
  for (int o = 0; o < 3; o++) {
    float v = s_b2[o] + s_w2[3 * o] * h[0] + s_w2[3 * o + 1] * h[1] + s_w2[3 * o + 2] * h[2];
    fb[o * 676 + pos] = f2bf(fmaxf(v, 0.f));
  }
}

// ---------------- K3: fc1 via MFMA + relu + fc2 + log_softmax ----------------
__global__ __launch_bounds__(512) void k_fc(
    const ushort* __restrict__ featB,  // [512][2048] bf16
    const ushort* __restrict__ WgtB,   // B-fragment layout
    const float* __restrict__ fc1_b,
    const float* __restrict__ fc2_w, const float* __restrict__ fc2_b,
    float* __restrict__ out)           // [512,10]
{
  __shared__ float s_f[16][132];
  __shared__ float s_lg[16][10];
  const int tid = threadIdx.x;
  const int lane = tid & 63;
  const int t = tid >> 6;           // N-tile 0..7
  const int m0 = blockIdx.x * 16;

  const ushort* aptr = featB + (size_t)(m0 + (lane & 15)) * 2048 + ((lane >> 4) << 3);
  const ushort* bptr = WgtB + ((size_t)t * 4096 + lane) * 8;

  f32x4 acc = {0.f, 0.f, 0.f, 0.f};
  #pragma unroll 4
  for (int kk = 0; kk < 64; kk++) {
    short8 a = *(const short8*)(aptr + kk * 32);
    short8 bfr = *(const short8*)(bptr + kk * 512);
    acc = __builtin_amdgcn_mfma_f32_16x16x32_bf16(a, bfr, acc, 0, 0, 0);
  }
  {
    int n = t * 16 + (lane & 15);
    float bias = fc1_b[n];
    int mb = (lane >> 4) << 2;
    #pragma unroll
    for (int r = 0; r < 4; r++)
      s_f[mb + r][n] = fmaxf(acc[r] + bias, 0.f);
  }
  __syncthreads();

  if (tid < 160) {
    int m = tid & 15, q = tid >> 4;
    const float* wr = fc2_w + q * 128;
    float a2 = fc2_b[q];
    #pragma unroll 8
    for (int n = 0; n < 128; n++) a2 += wr[n] * s_f[m][n];
    s_lg[m][q] = a2;
  }
  __syncthreads();

  if (tid < 16) {
    float mx = s_lg[tid][0];
    #pragma unroll
    for (int q = 1; q < 10; q++) mx = fmaxf(mx, s_lg[tid][q]);
    float se = 0.f;
    #pragma unroll
    for (int q = 0; q < 10; q++) se += expf(s_lg[tid][q] - mx);
    float lse = mx + logf(se);
    float* op = out + (size_t)(m0 + tid) * 10;
    #pragma unroll
    for (int q = 0; q < 10; q++) op[q] = s_lg[tid][q] - lse;
  }
}

extern "C" void kernel_launch(void* const* d_in, const int* in_sizes, int n_in,
                              void* d_out, int out_size, void* d_ws, size_t ws_size,
                              hipStream_t stream) {
  const float* x      = (const float*)d_in[0];
  const float* gamma  = (const float*)d_in[1];
  const float* beta   = (const float*)d_in[2];
  const float* w1     = (const float*)d_in[3];
  const float* b1     = (const float*)d_in[4];
  const float* w2     = (const float*)d_in[5];
  const float* b2     = (const float*)d_in[6];
  const float* fc1_w  = (const float*)d_in[7];
  const float* fc1_b  = (const float*)d_in[8];
  const float* fc2_w  = (const float*)d_in[9];
  const float* fc2_b  = (const float*)d_in[10];
  float* out = (float*)d_out;
  float* wsf = (float*)d_ws;

  float* stats  = wsf;                      // [0..5]
  float* psumA  = wsf + 64;                 // [6][6656]
  ushort* WgtB  = (ushort*)(wsf + 131072);  // 512 KB bf16
  ushort* featB = (ushort*)(wsf + 262144);  // 2 MB bf16
  float* S      = wsf + 786432;             // [9][NPOS] = 12.5 MB

  k_convwave<<<4992, 256, 0, stream>>>(x, w1, S, psumA);
  k_gather<<<128, 256, 0, stream>>>(fc1_w, WgtB, featB);
  k_reduce<<<6, 1024, 0, stream>>>(psumA, stats);
  k_combine<<<1352, 256, 0, stream>>>(S, stats, gamma, beta, w1, b1, w2, b2, featB);
  k_fc<<<32, 512, 0, stream>>>(featB, WgtB, fc1_b, fc2_w, fc2_b, out);
}